// Round 3
// baseline (17357.245 us; speedup 1.0000x reference)
//
#include <hip/hip_runtime.h>

// Encoder: 3-layer bidirectional-weights LSTM (both dirs scan forward per the
// reference), H=256, B=64, T=1024, then 256->81 linear + argmax (softmax is
// monotone -> dead code).
//
// R9: 512 blocks x 512 threads (2 blocks/CU). Each block owns ONE unit u of
// one direction d: 4 gate rows per task. 8 waves: w0-1 = L0 (40 k4 each),
// w2-4 = L1 (64 k4), w5-7 = L2 (64 k4). Rationale (R8 post-mortem): no pipe
// is saturated (VALUBusy 52%, HBM 2%, FMA floor ~19% of tick) -- the tick is
// stall-bound (vmcnt(0) LLC drains, epilogue syncthreads, ~1.3us serial grid
// barrier), and with one block/CU every stall idles the whole CU. Two
// independent blocks per CU overlap one block's stalls with the other's
// compute. LDS/block ~39 KB -> capacity 4 blocks/CU, so 512 co-resident is
// guaranteed (no barrier deadlock). red is now [8][64][4]: contiguous 16B
// per lane on both write and read (fixes R8's conflict-counter regression).
// FP grouping changes (wave slices); safe: int argmax output, absmax 0.0 with
// already-unrelated order.

#define H_ 256
#define B_ 64
#define T_ 1024
#define NBLK 512
#define NTHR 512
#define HBUF 98304     // floats per h ring buffer: 6 cells * 16384
#define NTICK 1026

// ws byte offsets
#define OFF_GEN  0
#define OFF_ROOT 64
#define OFF_CNT  128          // 16 counters, 64B apart (128..1152)
#define OFF_H    4096         // hbuf[2][6][16384] floats = 786432 B
#define OFF_XT   1048576      // xT2[1024][16][64][4] floats = 16 MB
#define OFF_YS   17825792     // ys[1024][64][256] floats = 64 MB

__device__ __forceinline__ float sigf(float x) {
  return 1.0f / (1.0f + __expf(-x));
}
__device__ __forceinline__ float tanhf_(float x) {
  float e = __expf(-2.0f * fabsf(x));
  float r = (1.0f - e) / (1.0f + e);
  return x >= 0.0f ? r : -r;
}

// ---- LLC-coherent (bypass L1/L2) access helpers ----
__device__ __forceinline__ void llc_ld1(const float4* p, float4& r) {
  asm volatile(
      "global_load_dwordx4 %0, %1, off sc0 sc1\n\t"
      "s_waitcnt vmcnt(0)"
      : "=v"(r)
      : "v"(p)
      : "memory");
}
__device__ __forceinline__ void llc_ld4(const float4* p, float4& r0, float4& r1,
                                        float4& r2, float4& r3) {
  asm volatile(
      "global_load_dwordx4 %0, %4, off sc0 sc1\n\t"
      "global_load_dwordx4 %1, %4, off offset:1024 sc0 sc1\n\t"
      "global_load_dwordx4 %2, %4, off offset:2048 sc0 sc1\n\t"
      "global_load_dwordx4 %3, %4, off offset:3072 sc0 sc1\n\t"
      "s_waitcnt vmcnt(0)"
      : "=&v"(r0), "=&v"(r1), "=&v"(r2), "=&v"(r3)
      : "v"(p)
      : "memory");
}
// 8 consecutive k4 rows, one drain. Two address regs (13-bit signed offset cap).
__device__ __forceinline__ void llc_ld8(const float4* p, const float4* q,
                                        float4& r0, float4& r1, float4& r2,
                                        float4& r3, float4& r4, float4& r5,
                                        float4& r6, float4& r7) {
  asm volatile(
      "global_load_dwordx4 %0, %8, off sc0 sc1\n\t"
      "global_load_dwordx4 %1, %8, off offset:1024 sc0 sc1\n\t"
      "global_load_dwordx4 %2, %8, off offset:2048 sc0 sc1\n\t"
      "global_load_dwordx4 %3, %8, off offset:3072 sc0 sc1\n\t"
      "global_load_dwordx4 %4, %9, off sc0 sc1\n\t"
      "global_load_dwordx4 %5, %9, off offset:1024 sc0 sc1\n\t"
      "global_load_dwordx4 %6, %9, off offset:2048 sc0 sc1\n\t"
      "global_load_dwordx4 %7, %9, off offset:3072 sc0 sc1\n\t"
      "s_waitcnt vmcnt(0)"
      : "=&v"(r0), "=&v"(r1), "=&v"(r2), "=&v"(r3), "=&v"(r4), "=&v"(r5),
        "=&v"(r6), "=&v"(r7)
      : "v"(p), "v"(q)
      : "memory");
}
// scalar h store, NO drain -- one shared vmcnt(0) before the barrier
__device__ __forceinline__ void llc_st1_nd(float* p, float v) {
  asm volatile("global_store_dword %0, %1, off sc0 sc1" ::"v"(p), "v"(v)
               : "memory");
}

// ---------------- x transpose: x[b][k][t] -> xT2[t][k>>2][b][k&3] ----------------
__global__ __launch_bounds__(64) void transpose_x(const float* __restrict__ x,
                                                  float* __restrict__ xT) {
  __shared__ float tile[64][65];
  const int k = blockIdx.y;
  const int t0 = blockIdx.x * 64;
  const int lane = threadIdx.x;
  for (int bi = 0; bi < 64; ++bi)
    tile[bi][lane] = x[bi * 65536 + k * 1024 + t0 + lane];
  __syncthreads();
  for (int ti = 0; ti < 64; ++ti)
    xT[(size_t)(t0 + ti) * 4096 + (k >> 2) * 256 + lane * 4 + (k & 3)] =
        tile[lane][ti];
}

// ---------------- 4-row FMA body for one k4 ----
// weights from LDS: wl[k4*16 + a*4 .. +3]  (wave-uniform ds_read_b128 broadcast)
__device__ __forceinline__ void body4(float* __restrict__ acc, const float4 av,
                                      const float* __restrict__ wl,
                                      const int k4) {
  const float* wp = wl + (size_t)k4 * 16;
#pragma unroll
  for (int a = 0; a < 4; ++a) {
    float4 wq = *(const float4*)(wp + a * 4);
    acc[a] += wq.x * av.x + wq.y * av.y + wq.z * av.z + wq.w * av.w;
  }
}

// LLC-path K runner: n k4-groups from bufbase starting at buffer k4 `bufk4`,
// weight index starting at task-global `wk4`. Batches of 8 / 4 / 1.
__device__ __forceinline__ void runLLC(float* __restrict__ acc,
                                       const float4* __restrict__ bufbase,
                                       const int bufk4, const int wk4,
                                       const int n,
                                       const float* __restrict__ wl,
                                       const int lane) {
  const float4* p = bufbase + (size_t)bufk4 * 64 + lane;
  int k = 0;
  for (; k + 8 <= n; k += 8) {
    float4 v0, v1, v2, v3, v4, v5, v6, v7;
    llc_ld8(p, p + 256, v0, v1, v2, v3, v4, v5, v6, v7);
    p += 512;
    body4(acc, v0, wl, wk4 + k + 0);
    body4(acc, v1, wl, wk4 + k + 1);
    body4(acc, v2, wl, wk4 + k + 2);
    body4(acc, v3, wl, wk4 + k + 3);
    body4(acc, v4, wl, wk4 + k + 4);
    body4(acc, v5, wl, wk4 + k + 5);
    body4(acc, v6, wl, wk4 + k + 6);
    body4(acc, v7, wl, wk4 + k + 7);
  }
  for (; k + 4 <= n; k += 4) {
    float4 v0, v1, v2, v3;
    llc_ld4(p, v0, v1, v2, v3);
    p += 256;
    body4(acc, v0, wl, wk4 + k + 0);
    body4(acc, v1, wl, wk4 + k + 1);
    body4(acc, v2, wl, wk4 + k + 2);
    body4(acc, v3, wl, wk4 + k + 3);
  }
  for (; k < n; ++k) {
    float4 v;
    llc_ld1(p, v);
    p += 64;
    body4(acc, v, wl, wk4 + k);
  }
}

// cached-path K runner (xT: written by earlier kernel, plain loads ok)
__device__ __forceinline__ void runCached(float* __restrict__ acc,
                                          const float4* __restrict__ bufbase,
                                          const int bufk4, const int wk4,
                                          const int n,
                                          const float* __restrict__ wl,
                                          const int lane) {
  const float4* p = bufbase + (size_t)bufk4 * 64 + lane;
  int k = 0;
  for (; k + 4 <= n; k += 4) {
    float4 v0 = p[0], v1 = p[64], v2 = p[128], v3 = p[192];
    p += 256;
    body4(acc, v0, wl, wk4 + k + 0);
    body4(acc, v1, wl, wk4 + k + 1);
    body4(acc, v2, wl, wk4 + k + 2);
    body4(acc, v3, wl, wk4 + k + 3);
  }
  for (; k < n; ++k) {
    float4 v = *p;
    p += 64;
    body4(acc, v, wl, wk4 + k);
  }
}

// ---------------- persistent skewed LSTM ----------------
__global__ __launch_bounds__(NTHR, 4) void lstm_persistent(
    const float* __restrict__ Wih0, const float* __restrict__ Whh0,
    const float* __restrict__ b0, const float* __restrict__ Wih12,
    const float* __restrict__ Whh12, const float* __restrict__ b12, char* wsb) {
  unsigned* gen = (unsigned*)(wsb + OFF_GEN);
  unsigned* root = (unsigned*)(wsb + OFF_ROOT);
  float* hb = (float*)(wsb + OFF_H);
  const float* xT = (const float*)(wsb + OFF_XT);
  float* ys = (float*)(wsb + OFF_YS);

  __shared__ float red[8][64][4];     // 8 KB
  __shared__ float cst[3][64];        // per-layer c state (0.75 KB)
  __shared__ float wlds[7424];        // 29.7 KB: [k4][4 rows][4] per task
  __shared__ float blds[3][4];        // biases per cell/gate

  const int bid = blockIdx.x;
  const int tid = threadIdx.x;
  const int lane = tid & 63;
  const int w = __builtin_amdgcn_readfirstlane(tid >> 6);  // uniform wave id 0..7
  const int d = bid >> 8;         // direction 0/1
  const int u = bid & 255;        // unit index

  if (tid < 192) ((float*)cst)[tid] = 0.f;

  // ---- stage this block's weights (4 rows per task) into LDS (once) ----
  auto stage = [&](const float* wA, int wAs, const float* wB, int wBs,
                   int K4s, int NA4s, float* dst) {
    const int nq = K4s * 4;
    for (int idx = tid; idx < nq; idx += NTHR) {
      const int a = idx / K4s;       // gate 0..3
      const int k4 = idx - a * K4s;
      const int row = a * 256 + u;
      const float* src = (k4 < NA4s) ? (wA + (size_t)row * wAs + k4 * 4)
                                     : (wB + (size_t)row * wBs + (k4 - NA4s) * 4);
      float4 q = *(const float4*)src;
      *(float4*)(dst + ((size_t)k4 * 4 + a) * 4) = q;
    }
  };
  stage(Wih0 + (size_t)d * 65536, 64, Whh0 + (size_t)d * 262144, 256, 80, 16,
        wlds);
  stage(Wih12 + (size_t)d * 524288, 512, Whh12 + (size_t)d * 262144, 256, 192,
        128, wlds + 1280);
  stage(Wih12 + (size_t)(2 + d) * 524288, 512,
        Whh12 + (size_t)(2 + d) * 262144, 256, 192, 128, wlds + 4352);
  // biases: blds[cell][a] = bias_cell[a*256 + u]
  if (tid < 12) {
    const int cell = tid >> 2, a = tid & 3;
    const float* bb = (cell == 0) ? (b0 + d * 1024)
                                  : ((cell == 1) ? (b12 + d * 1024)
                                                 : (b12 + (2 + d) * 1024));
    blds[cell][a] = bb[a * 256 + u];
  }
  __syncthreads();

  unsigned* mycnt = (unsigned*)(wsb + OFF_CNT + (size_t)(bid & 15) * 64);

  for (unsigned tick = 0; tick < NTICK; ++tick) {
    const float* R = hb + ((tick + 1) & 1) * HBUF;  // produced last tick
    float* W = hb + (tick & 1) * HBUF;              // produced this tick
    const float4* Rf4 = (const float4*)R;

    const bool has0 = tick < 1024;
    const bool has1 = tick >= 1 && tick < 1025;
    const bool has2 = tick >= 2;

    float acc[4] = {0.f, 0.f, 0.f, 0.f};

    // ---- concurrent task phase: waves 0-1 L0, 2-4 L1, 5-7 L2 ----
    if (w < 2) {
      if (has0) {
        // L0: K4=80 (16 x cached + 64 rec h LLC), 40 k4 per wave
        if (w == 0) {
          runCached(acc, (const float4*)xT + (size_t)tick * 1024, 0, 0, 16,
                    wlds, lane);
          runLLC(acc, Rf4 + (size_t)d * 4096, 0, 16, 24, wlds, lane);
        } else {
          runLLC(acc, Rf4 + (size_t)d * 4096, 24, 40, 40, wlds, lane);
        }
      }
    } else if (w < 5) {
      if (has1) {
        // L1: K4=192 (128 = cells 0,1 ; 64 = rec cell 2+d), 64 k4 per wave
        const int wi = w - 2;
        if (wi < 2)
          runLLC(acc, Rf4, wi * 64, wi * 64, 64, wlds + 1280, lane);
        else
          runLLC(acc, Rf4 + (size_t)(2 + d) * 4096, 0, 128, 64, wlds + 1280,
                 lane);
      }
    } else {
      if (has2) {
        // L2: K4=192 (128 = cells 2,3 ; 64 = rec cell 4+d), 64 k4 per wave
        const int wi = w - 5;
        if (wi < 2)
          runLLC(acc, Rf4 + (size_t)2 * 4096, wi * 64, wi * 64, 64,
                 wlds + 4352, lane);
        else
          runLLC(acc, Rf4 + (size_t)(4 + d) * 4096, 0, 128, 64, wlds + 4352,
                 lane);
      }
    }

    // partials -> LDS (contiguous 16B per lane: conflict-free)
    *(float4*)&red[w][lane][0] = make_float4(acc[0], acc[1], acc[2], acc[3]);
    __syncthreads();

    // ---- fused epilogue: 192 threads = 3 cells x 64 batch ----
    if (tid < 192) {
      const int cell = tid >> 6, b = tid & 63;
      const bool present = (cell == 0) ? has0 : ((cell == 1) ? has1 : has2);
      if (present) {
        const int w0c = (cell == 0) ? 0 : ((cell == 1) ? 2 : 5);
        const int nw = (cell == 0) ? 2 : 3;
        float g0 = blds[cell][0], g1 = blds[cell][1], g2 = blds[cell][2],
              g3 = blds[cell][3];
        for (int ww = w0c; ww < w0c + nw; ++ww) {
          float4 s = *(const float4*)&red[ww][b][0];
          g0 += s.x; g1 += s.y; g2 += s.z; g3 += s.w;
        }
        const float iv = sigf(g0), fv = sigf(g1), gv = tanhf_(g2),
                    ov = sigf(g3);
        float c = fv * cst[cell][b] + iv * gv;
        cst[cell][b] = c;
        const float h = ov * tanhf_(c);
        const int cellidx = (cell == 0) ? d : ((cell == 1) ? (2 + d) : (4 + d));
        float* hp =
            W + (size_t)cellidx * 16384 + (u >> 2) * 256 + b * 4 + (u & 3);
        llc_st1_nd(hp, h);  // no drain; shared drain below
        if (cell == 2 && d == 1) {
          // plain cached store: consumed by conv_argmax after kernel end
          ys[(size_t)((int)tick - 2) * 16384 + b * 256 + u] = h;
        }
      }
    }
    // single drain for all h stores, then block barrier
    asm volatile("s_waitcnt vmcnt(0)" ::: "memory");
    __syncthreads();

    // -------- grid barrier: pure relaxed LLC atomics, NO fences --------
    if (tid == 0) {
      unsigned old = __hip_atomic_fetch_add(mycnt, 1u, __ATOMIC_RELAXED,
                                            __HIP_MEMORY_SCOPE_AGENT);
      if (old == (tick + 1) * (NBLK / 16) - 1) {
        unsigned r = __hip_atomic_fetch_add(root, 1u, __ATOMIC_RELAXED,
                                            __HIP_MEMORY_SCOPE_AGENT);
        if (r == (tick + 1) * 16 - 1) {
          __hip_atomic_store(gen, tick + 1, __ATOMIC_RELAXED,
                             __HIP_MEMORY_SCOPE_AGENT);
        }
      }
      while (__hip_atomic_load(gen, __ATOMIC_RELAXED, __HIP_MEMORY_SCOPE_AGENT) <
             tick + 1) {
        __builtin_amdgcn_s_sleep(2);
      }
    }
    __syncthreads();
  }
}

// ---------------- conv(256->81) + argmax ----------------
__global__ __launch_bounds__(256) void conv_argmax(const float* __restrict__ yst,
                                                   const float* __restrict__ cw,
                                                   const float* __restrict__ cb,
                                                   int* __restrict__ out) {
  const int t = blockIdx.x;
  const int tid = threadIdx.x, lane = tid & 63, w = tid >> 6;
  const float* yrow = yst + (size_t)t * (B_ * H_) + lane * H_;
  float best = -3.4e38f;
  int bi = 0;
  for (int og = 0; og < 3; ++og) {
    float acc[8];
    int ov[8];
#pragma unroll
    for (int m = 0; m < 8; ++m) {
      int o = w + 32 * og + 4 * m;
      ov[m] = (o < 81) ? o : 80;
      acc[m] = (o < 81) ? cb[o] : -3.4e38f;
    }
    for (int uu = 0; uu < H_; uu += 4) {
      float4 y4 = *(const float4*)(yrow + uu);
#pragma unroll
      for (int m = 0; m < 8; ++m) {
        const float* wr = cw + ov[m] * H_ + uu;
        acc[m] += wr[0] * y4.x + wr[1] * y4.y + wr[2] * y4.z + wr[3] * y4.w;
      }
    }
#pragma unroll
    for (int m = 0; m < 8; ++m) {
      int o = w + 32 * og + 4 * m;
      if (o < 81 && acc[m] > best) {
        best = acc[m];
        bi = o;
      }
    }
  }
  __shared__ float sv[4][64];
  __shared__ int si[4][64];
  sv[w][lane] = best;
  si[w][lane] = bi;
  __syncthreads();
  if (tid < 64) {
    float bv = sv[0][tid];
    int bo = si[0][tid];
#pragma unroll
    for (int ww = 1; ww < 4; ++ww) {
      float v = sv[ww][tid];
      int o = si[ww][tid];
      if (v > bv || (v == bv && o < bo)) {
        bv = v;
        bo = o;
      }
    }
    out[tid * T_ + t] = bo;
  }
}

extern "C" void kernel_launch(void* const* d_in, const int* in_sizes, int n_in,
                              void* d_out, int out_size, void* d_ws,
                              size_t ws_size, hipStream_t stream) {
  const float* x = (const float*)d_in[0];
  const float* Wih0 = (const float*)d_in[1];
  const float* Whh0 = (const float*)d_in[2];
  const float* b0 = (const float*)d_in[3];
  const float* Wih12 = (const float*)d_in[4];
  const float* Whh12 = (const float*)d_in[5];
  const float* b12 = (const float*)d_in[6];
  const float* cw = (const float*)d_in[7];
  const float* cb = (const float*)d_in[8];
  int* out = (int*)d_out;
  char* wsb = (char*)d_ws;

  // zero flags + h ring (ws is re-poisoned 0xAA before every launch)
  hipMemsetAsync(wsb, 0, OFF_H + 786432, stream);
  transpose_x<<<dim3(16, 64, 1), dim3(64, 1, 1), 0, stream>>>(
      x, (float*)(wsb + OFF_XT));
  lstm_persistent<<<dim3(NBLK, 1, 1), dim3(NTHR, 1, 1), 0, stream>>>(
      Wih0, Whh0, b0, Wih12, Whh12, b12, wsb);
  conv_argmax<<<dim3(T_, 1, 1), dim3(256, 1, 1), 0, stream>>>(
      (const float*)(wsb + OFF_YS), cw, cb, out);
}